// Round 7
// baseline (215.421 us; speedup 1.0000x reference)
//
#include <hip/hip_runtime.h>

#define N_NODES 20000
#define N_EDGES 160000
#define N_PAIRS 50000
#define DMAX 48
// F_IN = CHANNELS = 32, EDGE_DIM = 8

__device__ __forceinline__ float4 f4fma(float s, float4 w, float4 acc) {
    acc.x += s * w.x; acc.y += s * w.y; acc.z += s * w.z; acc.w += s * w.w;
    return acc;
}

// ---------------- zero counters ----------------
__global__ void zero_cnts(int* __restrict__ c) {
    int t = blockIdx.x * blockDim.x + threadIdx.x;
    if (t < 2 * N_NODES) c[t] = 0;
}

// ---------------- dual adjacency fill: slot tables by src and by tgt ----------------
__global__ __launch_bounds__(256) void fill_both(const int* __restrict__ ei,
                                                 int* __restrict__ cnt_src,
                                                 int* __restrict__ cnt_tgt,
                                                 int* __restrict__ srcEid,
                                                 int* __restrict__ tgtEid) {
    int e0 = blockIdx.x * blockDim.x + threadIdx.x;
    if (e0 >= N_EDGES) return;
    int2 st = ((const int2*)ei)[e0];  // x = src, y = tgt
    int ss = atomicAdd(&cnt_src[st.x], 1);
    if (ss < DMAX) srcEid[st.x * DMAX + ss] = e0;
    int ts = atomicAdd(&cnt_tgt[st.y], 1);
    if (ts < DMAX) tgtEid[st.y * DMAX + ts] = e0;
}

// ---------------- fused node GEMM + per-edge message materialization ----------------
// Y[n][c] = sum_i X[n][i] * W2[i][c]  with fused W2 (knw | knb | root), 32 nodes/block.
// Then Y is parked in LDS (stride 324 to break bank aliasing) and this block's
// out-edges get their 32-channel messages computed from LDS and written to msg[eid].
// msg[e][o] = Y[src][256+o] + sum_d E[e][d]*Y[src][d*32+o]   (B-term included)
// Hroot[n][o] = Y[n][288+o]  (root-term, needed by the target-side pass)
__global__ __launch_bounds__(320) void gemm_msg(const float* __restrict__ X,
                                                const float* __restrict__ knw,
                                                const float* __restrict__ knb,
                                                const float* __restrict__ root,
                                                const float* __restrict__ E,
                                                const int* __restrict__ cnt_src,
                                                const int* __restrict__ srcEid,
                                                float* __restrict__ Hroot,
                                                float4* __restrict__ msg4) {
    __shared__ float Ws[32 * 324];   // phase A: W2 at stride 320; phase B: YL at stride 324
    __shared__ float Xs[32 * 32];
    __shared__ int   list[32 * DMAX];
    __shared__ int   cntS[32];
    __shared__ int   offS[33];
    int t = threadIdx.x;
    int nodebase = blockIdx.x * 32;

    // build fused W2 into LDS (stride 320): c = t, loop i
    {
        int c = t;
#pragma unroll
        for (int i = 0; i < 32; ++i) {
            float v;
            if (c < 256) { int d = c >> 5, o = c & 31; v = knw[d * 1024 + i * 32 + o]; }
            else if (c < 288) { v = knb[i * 32 + (c - 256)]; }
            else { v = root[i * 32 + (c - 288)]; }
            Ws[i * 320 + c] = v;
        }
    }
    const float4* x4 = (const float4*)(X + nodebase * 32);
    float4* Xs4 = (float4*)Xs;
    if (t < 256) Xs4[t] = x4[t];
    if (t < 32) cntS[t] = min(cnt_src[nodebase + t], DMAX);
    __syncthreads();

    // GEMM: thread (q,g) -> cols 4q..4q+3 of nodes g*8..g*8+7
    float4* Ws4 = (float4*)Ws;
    int q = t % 80, g = t / 80;
    float4 acc[8];
#pragma unroll
    for (int m = 0; m < 8; ++m) acc[m] = make_float4(0.f, 0.f, 0.f, 0.f);
#pragma unroll
    for (int i4 = 0; i4 < 8; ++i4) {
        float4 w0 = Ws4[(i4 * 4 + 0) * 80 + q];
        float4 w1 = Ws4[(i4 * 4 + 1) * 80 + q];
        float4 w2r = Ws4[(i4 * 4 + 2) * 80 + q];
        float4 w3 = Ws4[(i4 * 4 + 3) * 80 + q];
#pragma unroll
        for (int m = 0; m < 8; ++m) {
            float4 xv = Xs4[(g * 8 + m) * 8 + i4];
            acc[m] = f4fma(xv.x, w0, acc[m]);
            acc[m] = f4fma(xv.y, w1, acc[m]);
            acc[m] = f4fma(xv.z, w2r, acc[m]);
            acc[m] = f4fma(xv.w, w3, acc[m]);
        }
    }
    __syncthreads();  // all W2 reads done; Ws becomes YL (stride 324)

    // park Y in LDS; spill root-term cols to global
#pragma unroll
    for (int m = 0; m < 8; ++m) {
        int node = g * 8 + m;
        *(float4*)&Ws[node * 324 + q * 4] = acc[m];
        if (q >= 72)
            ((float4*)(Hroot + (nodebase + node) * 32))[q - 72] = acc[m];
    }
    // compact out-edge list for this block's 32 src nodes (wave 0, lanes 0..31)
    if (t < 32) {
        int c = cntS[t];
        int v = c;
#pragma unroll
        for (int d = 1; d < 32; d <<= 1) {
            int u = __shfl_up(v, d, 32);
            if (t >= d) v += u;
        }
        int off = v - c;
        offS[t] = off;
        if (t == 31) offS[32] = v;
        for (int k = 0; k < c; ++k) list[off + k] = t * DMAX + k;
    }
    __syncthreads();

    // message loop: 40 groups of 8 lanes; group handles one edge per iteration
    int nE = offS[32];
    int grp = t >> 3, lq = t & 7;
    for (int idx = grp; idx < nE; idx += 40) {
        int packed = list[idx];              // node*DMAX + k
        int node = packed / DMAX;
        int eid = srcEid[nodebase * DMAX + packed];
        float ev = E[eid * 8 + lq];          // lane lq holds e[lq]
        const float* yl = &Ws[node * 324];
        float4 m = *(const float4*)&yl[256 + lq * 4];  // B-term
#pragma unroll
        for (int d = 0; d < 8; ++d) {
            float ed = __shfl(ev, d, 8);
            m = f4fma(ed, *(const float4*)&yl[d * 32 + lq * 4], m);
        }
        msg4[eid * 8 + lq] = m;
    }
}

// ---------------- target-side aggregation: lane o = channel, 2 nodes/wave -------
__global__ __launch_bounds__(256) void seg_layer1(const float* __restrict__ msg,
                                                  const int* __restrict__ cnt_tgt,
                                                  const int* __restrict__ tgtEid,
                                                  const float* __restrict__ Hroot,
                                                  const float* __restrict__ bias,
                                                  float* __restrict__ H) {
    int t = blockIdx.x * blockDim.x + threadIdx.x;
    int n = t >> 5;
    if (n >= N_NODES) return;
    int o = t & 31;
    int deg = min(cnt_tgt[n], DMAX);
    const int* te = tgtEid + n * DMAX;
    float acc = 0.f;
    for (int k = 0; k < deg; ++k) {
        int eid = te[k];
        acc += msg[eid * 32 + o];
    }
    float v = acc + Hroot[n * 32 + o] + bias[o];
    H[n * 32 + o] = fmaxf(v, 0.f);
}

// layer 2 + readout fused: util[n] = db + sum_o relu(...)*dw[o]
__global__ __launch_bounds__(256) void seg_layer2_util(const float* __restrict__ msg,
                                                       const int* __restrict__ cnt_tgt,
                                                       const int* __restrict__ tgtEid,
                                                       const float* __restrict__ Hroot,
                                                       const float* __restrict__ bias,
                                                       const float* __restrict__ dw,
                                                       const float* __restrict__ db,
                                                       float* __restrict__ util) {
    int t = blockIdx.x * blockDim.x + threadIdx.x;
    int n = t >> 5;
    if (n >= N_NODES) return;
    int o = t & 31;
    int deg = min(cnt_tgt[n], DMAX);
    const int* te = tgtEid + n * DMAX;
    float acc = 0.f;
    for (int k = 0; k < deg; ++k) {
        int eid = te[k];
        acc += msg[eid * 32 + o];
    }
    float v = fmaxf(acc + Hroot[n * 32 + o] + bias[o], 0.f);
    float p = v * dw[o];
    p += __shfl_xor(p, 1);
    p += __shfl_xor(p, 2);
    p += __shfl_xor(p, 4);
    p += __shfl_xor(p, 8);
    p += __shfl_xor(p, 16);
    if (o == 0) util[n] = p + db[0];
}

// out[p] = util[idx_b[p]] - util[idx_a[p]]
__global__ void pair_kernel(const float* __restrict__ util, const int* __restrict__ ia,
                            const int* __restrict__ ib, float* __restrict__ out) {
    int p = blockIdx.x * blockDim.x + threadIdx.x;
    if (p >= N_PAIRS) return;
    out[p] = util[ib[p]] - util[ia[p]];
}

extern "C" void kernel_launch(void* const* d_in, const int* in_sizes, int n_in,
                              void* d_out, int out_size, void* d_ws, size_t ws_size,
                              hipStream_t stream) {
    const float* x     = (const float*)d_in[0];
    const float* e     = (const float*)d_in[1];
    const float* knw1  = (const float*)d_in[2];
    const float* knb1  = (const float*)d_in[3];
    const float* root1 = (const float*)d_in[4];
    const float* bias1 = (const float*)d_in[5];
    const float* knw2  = (const float*)d_in[6];
    const float* knb2  = (const float*)d_in[7];
    const float* root2 = (const float*)d_in[8];
    const float* bias2 = (const float*)d_in[9];
    const float* dw    = (const float*)d_in[10];
    const float* db    = (const float*)d_in[11];
    const int*   ei    = (const int*)d_in[12];
    const int*   ia    = (const int*)d_in[13];
    const int*   ib    = (const int*)d_in[14];
    float* out = (float*)d_out;

    float* ws = (float*)d_ws;
    float* msg    = ws;                        // 5,120,000 floats (160000*32)
    float* Hroot1 = ws + 5120000;              // 640,000
    float* Hroot2 = ws + 5760000;              // 640,000
    float* H      = ws + 6400000;              // 640,000
    float* util   = ws + 7040000;              // 20,000
    int*   cnts   = (int*)(ws + 7060000);      // cnt_src[20000] + cnt_tgt[20000]
    int*   cnt_src = cnts;
    int*   cnt_tgt = cnts + N_NODES;
    int*   srcEid = (int*)(ws + 7100000);      // 960,000
    int*   tgtEid = (int*)(ws + 8060000);      // 960,000

    // ---- adjacency ----
    zero_cnts<<<(2 * N_NODES + 255) / 256, 256, 0, stream>>>(cnts);
    fill_both<<<(N_EDGES + 255) / 256, 256, 0, stream>>>(ei, cnt_src, cnt_tgt,
                                                         srcEid, tgtEid);

    // ---- layer 1 ----
    gemm_msg<<<N_NODES / 32, 320, 0, stream>>>(x, knw1, knb1, root1, e,
                                               cnt_src, srcEid, Hroot1, (float4*)msg);
    seg_layer1<<<(N_NODES * 32) / 256, 256, 0, stream>>>(msg, cnt_tgt, tgtEid,
                                                         Hroot1, bias1, H);

    // ---- layer 2 (+ readout) ----
    gemm_msg<<<N_NODES / 32, 320, 0, stream>>>(H, knw2, knb2, root2, e,
                                               cnt_src, srcEid, Hroot2, (float4*)msg);
    seg_layer2_util<<<(N_NODES * 32) / 256, 256, 0, stream>>>(msg, cnt_tgt, tgtEid,
                                                              Hroot2, bias2, dw, db, util);

    // ---- pairs ----
    pair_kernel<<<(N_PAIRS + 255) / 256, 256, 0, stream>>>(util, ia, ib, out);
}

// Round 8
// 110.182 us; speedup vs baseline: 1.9551x; 1.9551x over previous
//
#include <hip/hip_runtime.h>

#define N_NODES 20000
#define N_EDGES 160000
#define N_PAIRS 50000
#define DMAX 48
#define EPI_NODES 80
// F_IN = CHANNELS = 32, EDGE_DIM = 8

__device__ __forceinline__ float4 f4fma(float s, float4 w, float4 a) {
    a.x += s * w.x; a.y += s * w.y; a.z += s * w.z; a.w += s * w.w;
    return a;
}

__global__ void zero_cnt(int* __restrict__ c) {
    int t = blockIdx.x * blockDim.x + threadIdx.x;
    if (t < N_NODES) c[t] = 0;
}

// adjacency by target: slot -> (src node, edge id)
__global__ __launch_bounds__(256) void fill_adj(const int* __restrict__ ei,
                                                int* __restrict__ cnt,
                                                int* __restrict__ adjsrc,
                                                int* __restrict__ adjeid) {
    int e = blockIdx.x * blockDim.x + threadIdx.x;
    if (e >= N_EDGES) return;
    int2 st = ((const int2*)ei)[e];  // x = src, y = tgt
    int slot = atomicAdd(&cnt[st.y], 1);
    if (slot < DMAX) {
        int idx = st.y * DMAX + slot;
        adjsrc[idx] = st.x;
        adjeid[idx] = e;
    }
}

// Edge phase: per-target sufficient statistic G (gathers only x[src], 128B/edge).
// G[n][d*32+i] = sum_{e->n} e_d * X[src_e][i]  (d=0..7)
// G[n][256+i]  = sum_{e->n} X[src_e][i]        (knb term)
// G[n][288+i]  = X[n][i]                        (root term)
// 32 lanes per target (lane = channel i), 8 targets per 256-thread block.
__global__ __launch_bounds__(256) void edge_gather(const float* __restrict__ X,
                                                   const float* __restrict__ E,
                                                   const int* __restrict__ cnt,
                                                   const int* __restrict__ adjsrc,
                                                   const int* __restrict__ adjeid,
                                                   float* __restrict__ G) {
    int t = blockIdx.x * blockDim.x + threadIdx.x;
    int n = t >> 5;
    if (n >= N_NODES) return;
    int lane = t & 31;
    int deg = min(cnt[n], DMAX);
    float g0 = 0.f, g1 = 0.f, g2 = 0.f, g3 = 0.f;
    float g4 = 0.f, g5 = 0.f, g6 = 0.f, g7 = 0.f, g8 = 0.f;
    int base = n * DMAX;
    for (int k = 0; k < deg; ++k) {
        int src = adjsrc[base + k];
        int eid = adjeid[base + k];
        const float4* e4 = (const float4*)(E + (size_t)eid * 8);
        float4 ea = e4[0], eb = e4[1];     // uniform within half-wave
        float xv = X[src * 32 + lane];     // coalesced 128B line, L2-resident
        g0 += ea.x * xv; g1 += ea.y * xv; g2 += ea.z * xv; g3 += ea.w * xv;
        g4 += eb.x * xv; g5 += eb.y * xv; g6 += eb.z * xv; g7 += eb.w * xv;
        g8 += xv;
    }
    float* gr = G + (size_t)n * 320;
    gr[0 * 32 + lane] = g0; gr[1 * 32 + lane] = g1;
    gr[2 * 32 + lane] = g2; gr[3 * 32 + lane] = g3;
    gr[4 * 32 + lane] = g4; gr[5 * 32 + lane] = g5;
    gr[6 * 32 + lane] = g6; gr[7 * 32 + lane] = g7;
    gr[256 + lane] = g8;
    gr[288 + lane] = X[n * 32 + lane];
}

// Epilogue GEMM: out[n][o] = sum_k G[n][k] * W'[k][o], K=320, N=32.
// W' = [knw | knb | root] VERBATIM (knw[d*1024+i*32+o] == W'[(d*32+i)*32+o]).
// mode 0: H[n][o] = relu(out + bias[o])
// mode 1: util[n] = db + sum_o relu(out + bias[o]) * dw[o]
// 256 blocks x 80 nodes; thread (mg=t>>3, j=t&7) computes nodes {mg, mg+32, mg+64<80}
// x outputs 4j..4j+3. Gs staged k-half at a time, stride 164 (bank-spread, 16B-aligned).
__global__ __launch_bounds__(256) void epi_gemm(const float* __restrict__ G,
                                                const float* __restrict__ knw,
                                                const float* __restrict__ knb,
                                                const float* __restrict__ root,
                                                const float* __restrict__ bias,
                                                const float* __restrict__ dw,
                                                const float* __restrict__ db,
                                                float* __restrict__ H,
                                                float* __restrict__ util,
                                                int mode) {
    __shared__ float Ws[320 * 32];          // 40960 B
    __shared__ float Gs[EPI_NODES * 164];   // 52480 B
    int t = threadIdx.x;
    int nb = blockIdx.x * EPI_NODES;

    // stage W' verbatim
    {
        float4* d = (float4*)Ws;
        const float4* s1 = (const float4*)knw;   // 2048 f4
        for (int i = t; i < 2048; i += 256) d[i] = s1[i];
        const float4* s2 = (const float4*)knb;   // 256 f4
        d[2048 + t] = s2[t];
        const float4* s3 = (const float4*)root;  // 256 f4
        d[2304 + t] = s3[t];
    }

    int mg = t >> 3, j = t & 7;
    float4 a0 = make_float4(0.f, 0.f, 0.f, 0.f);
    float4 a1 = a0, a2 = a0;

#pragma unroll
    for (int half = 0; half < 2; ++half) {
        __syncthreads();  // Ws ready / previous Gs consumed
        for (int idx = t; idx < EPI_NODES * 40; idx += 256) {
            int r = idx / 40, c = idx % 40;
            float4 v = ((const float4*)(G + (size_t)(nb + r) * 320 + half * 160))[c];
            *(float4*)&Gs[r * 164 + c * 4] = v;
        }
        __syncthreads();
        int kbase = half * 160;
        for (int k4 = 0; k4 < 40; ++k4) {
            const float* wr = &Ws[(kbase + k4 * 4) * 32 + j * 4];
            float4 w0 = *(const float4*)(wr);
            float4 w1 = *(const float4*)(wr + 32);
            float4 w2 = *(const float4*)(wr + 64);
            float4 w3 = *(const float4*)(wr + 96);
            float4 gA = *(const float4*)&Gs[mg * 164 + k4 * 4];
            a0 = f4fma(gA.x, w0, a0); a0 = f4fma(gA.y, w1, a0);
            a0 = f4fma(gA.z, w2, a0); a0 = f4fma(gA.w, w3, a0);
            float4 gB = *(const float4*)&Gs[(mg + 32) * 164 + k4 * 4];
            a1 = f4fma(gB.x, w0, a1); a1 = f4fma(gB.y, w1, a1);
            a1 = f4fma(gB.z, w2, a1); a1 = f4fma(gB.w, w3, a1);
            if (mg < 16) {
                float4 gC = *(const float4*)&Gs[(mg + 64) * 164 + k4 * 4];
                a2 = f4fma(gC.x, w0, a2); a2 = f4fma(gC.y, w1, a2);
                a2 = f4fma(gC.z, w2, a2); a2 = f4fma(gC.w, w3, a2);
            }
        }
    }

    float4 b = ((const float4*)bias)[j];
    if (mode == 0) {
        float4* H4 = (float4*)H;
        int n0 = nb + mg;
        {
            float4 v;
            v.x = fmaxf(a0.x + b.x, 0.f); v.y = fmaxf(a0.y + b.y, 0.f);
            v.z = fmaxf(a0.z + b.z, 0.f); v.w = fmaxf(a0.w + b.w, 0.f);
            if (n0 < N_NODES) H4[n0 * 8 + j] = v;
        }
        int n1 = nb + mg + 32;
        {
            float4 v;
            v.x = fmaxf(a1.x + b.x, 0.f); v.y = fmaxf(a1.y + b.y, 0.f);
            v.z = fmaxf(a1.z + b.z, 0.f); v.w = fmaxf(a1.w + b.w, 0.f);
            if (n1 < N_NODES) H4[n1 * 8 + j] = v;
        }
        int n2 = nb + mg + 64;
        if (mg < 16) {
            float4 v;
            v.x = fmaxf(a2.x + b.x, 0.f); v.y = fmaxf(a2.y + b.y, 0.f);
            v.z = fmaxf(a2.z + b.z, 0.f); v.w = fmaxf(a2.w + b.w, 0.f);
            if (n2 < N_NODES) H4[n2 * 8 + j] = v;
        }
    } else {
        float4 dv = ((const float4*)dw)[j];
        float dbv = db[0];
        {
            float p = fmaxf(a0.x + b.x, 0.f) * dv.x + fmaxf(a0.y + b.y, 0.f) * dv.y
                    + fmaxf(a0.z + b.z, 0.f) * dv.z + fmaxf(a0.w + b.w, 0.f) * dv.w;
            p += __shfl_xor(p, 1, 8);
            p += __shfl_xor(p, 2, 8);
            p += __shfl_xor(p, 4, 8);
            int n0 = nb + mg;
            if (j == 0 && n0 < N_NODES) util[n0] = p + dbv;
        }
        {
            float p = fmaxf(a1.x + b.x, 0.f) * dv.x + fmaxf(a1.y + b.y, 0.f) * dv.y
                    + fmaxf(a1.z + b.z, 0.f) * dv.z + fmaxf(a1.w + b.w, 0.f) * dv.w;
            p += __shfl_xor(p, 1, 8);
            p += __shfl_xor(p, 2, 8);
            p += __shfl_xor(p, 4, 8);
            int n1 = nb + mg + 32;
            if (j == 0 && n1 < N_NODES) util[n1] = p + dbv;
        }
        if (mg < 16) {
            float p = fmaxf(a2.x + b.x, 0.f) * dv.x + fmaxf(a2.y + b.y, 0.f) * dv.y
                    + fmaxf(a2.z + b.z, 0.f) * dv.z + fmaxf(a2.w + b.w, 0.f) * dv.w;
            p += __shfl_xor(p, 1, 8);
            p += __shfl_xor(p, 2, 8);
            p += __shfl_xor(p, 4, 8);
            int n2 = nb + mg + 64;
            if (j == 0 && n2 < N_NODES) util[n2] = p + dbv;
        }
    }
}

// out[p] = util[idx_b[p]] - util[idx_a[p]]
__global__ void pair_kernel(const float* __restrict__ util, const int* __restrict__ ia,
                            const int* __restrict__ ib, float* __restrict__ out) {
    int p = blockIdx.x * blockDim.x + threadIdx.x;
    if (p >= N_PAIRS) return;
    out[p] = util[ib[p]] - util[ia[p]];
}

extern "C" void kernel_launch(void* const* d_in, const int* in_sizes, int n_in,
                              void* d_out, int out_size, void* d_ws, size_t ws_size,
                              hipStream_t stream) {
    const float* x     = (const float*)d_in[0];
    const float* e     = (const float*)d_in[1];
    const float* knw1  = (const float*)d_in[2];
    const float* knb1  = (const float*)d_in[3];
    const float* root1 = (const float*)d_in[4];
    const float* bias1 = (const float*)d_in[5];
    const float* knw2  = (const float*)d_in[6];
    const float* knb2  = (const float*)d_in[7];
    const float* root2 = (const float*)d_in[8];
    const float* bias2 = (const float*)d_in[9];
    const float* dw    = (const float*)d_in[10];
    const float* db    = (const float*)d_in[11];
    const int*   ei    = (const int*)d_in[12];
    const int*   ia    = (const int*)d_in[13];
    const int*   ib    = (const int*)d_in[14];
    float* out = (float*)d_out;

    float* ws = (float*)d_ws;
    float* G      = ws;                       // 20480*320 = 6,553,600 floats
    float* H      = ws + 6553600;             // 640,000
    float* util   = ws + 7193600;             // 20,000
    int*   cnt    = (int*)(ws + 7213600);     // 20,000
    int*   adjsrc = (int*)(ws + 7233600);     // 960,000
    int*   adjeid = (int*)(ws + 8193600);     // 960,000

    // ---- adjacency ----
    zero_cnt<<<(N_NODES + 255) / 256, 256, 0, stream>>>(cnt);
    fill_adj<<<(N_EDGES + 255) / 256, 256, 0, stream>>>(ei, cnt, adjsrc, adjeid);

    // ---- layer 1 ----
    edge_gather<<<(N_NODES * 32) / 256, 256, 0, stream>>>(x, e, cnt, adjsrc, adjeid, G);
    epi_gemm<<<256, 256, 0, stream>>>(G, knw1, knb1, root1, bias1, dw, db, H, util, 0);

    // ---- layer 2 (+ readout) ----
    edge_gather<<<(N_NODES * 32) / 256, 256, 0, stream>>>(H, e, cnt, adjsrc, adjeid, G);
    epi_gemm<<<256, 256, 0, stream>>>(G, knw2, knb2, root2, bias2, dw, db, H, util, 1);

    // ---- pairs ----
    pair_kernel<<<(N_PAIRS + 255) / 256, 256, 0, stream>>>(util, ia, ib, out);
}